// Round 1
// baseline (1292.668 us; speedup 1.0000x reference)
//
#include <hip/hip_runtime.h>
#include <math.h>

#define NN 20000
#define NE 320000
#define D 50
#define TOWERS 5
#define TD 250      // TOWERS*D
#define FOUT 10
#define EPS 1e-5f

// ------------------------------------------------------------------ setup
__global__ void k_deg(const int* __restrict__ dst, int* __restrict__ deg) {
    int e = blockIdx.x * 256 + threadIdx.x;
    if (e < NE) atomicAdd(&deg[dst[e]], 1);
}

__global__ void k_scan(const int* __restrict__ deg, int* __restrict__ offs) {
    __shared__ int buf[1024];
    __shared__ int carry;
    int tid = threadIdx.x;
    if (tid == 0) carry = 0;
    __syncthreads();
    for (int base = 0; base < NN; base += 1024) {
        int i = base + tid;
        int v = (i < NN) ? deg[i] : 0;
        buf[tid] = v;
        __syncthreads();
        for (int off = 1; off < 1024; off <<= 1) {
            int t = (tid >= off) ? buf[tid - off] : 0;
            __syncthreads();
            buf[tid] += t;
            __syncthreads();
        }
        int excl = carry + buf[tid] - v;   // exclusive prefix
        if (i < NN) offs[i] = excl;
        __syncthreads();
        if (tid == 0) carry += buf[1023];
        __syncthreads();
    }
    if (tid == 0) offs[NN] = carry;        // == NE
}

__global__ void k_csr(const int* __restrict__ src, const int* __restrict__ dst,
                      const int* __restrict__ offs, int* __restrict__ cursor,
                      int* __restrict__ csr_src) {
    int e = blockIdx.x * 256 + threadIdx.x;
    if (e < NE) {
        int d = dst[e];
        int slot = atomicAdd(&cursor[d], 1);
        csr_src[offs[d] + slot] = src[e];
    }
}

__global__ void k_avglog(const int* __restrict__ deg, float* __restrict__ accum) {
    int n = blockIdx.x * 256 + threadIdx.x;
    float v = (n < NN) ? logf((float)deg[n] + 1.0f) : 0.0f;
    for (int o = 32; o > 0; o >>= 1) v += __shfl_down(v, o);
    __shared__ float wsum[4];
    int lane = threadIdx.x & 63, w = threadIdx.x >> 6;
    if (lane == 0) wsum[w] = v;
    __syncthreads();
    if (threadIdx.x == 0) atomicAdd(accum, wsum[0] + wsum[1] + wsum[2] + wsum[3]);
}

__global__ void k_emb(const int* __restrict__ x, const float* __restrict__ emb,
                      float* __restrict__ h) {
    int idx = blockIdx.x * 256 + threadIdx.x;
    if (idx < NN * D) {
        int n = idx / D, c = idx % D;
        h[idx] = emb[x[n] * D + c];
    }
}

// ------------------------------------------------------------- per layer
// ai/aj: per-node pre-NN split (x_i part / x_j part). Tile 64 nodes in LDS,
// each thread owns one of the 250 output features, W row in registers.
#define PRE_NT 64
__global__ __launch_bounds__(256) void k_pre(const float* __restrict__ h,
                                             const float* __restrict__ preW, // [TD][2D]
                                             float* __restrict__ ai,
                                             float* __restrict__ aj) {
    __shared__ float xl[PRE_NT * 52];
    int n0 = blockIdx.x * PRE_NT;
    int nmax = min(PRE_NT, NN - n0);
    for (int k = threadIdx.x; k < nmax * D; k += 256) {
        int nl = k / D, f = k % D;
        xl[nl * 52 + f] = h[(n0 + nl) * D + f];
    }
    __syncthreads();
    int o = threadIdx.x;
    if (o < TD) {
        const float* w0 = preW + o * (2 * D);
        float wi[D], wj[D];
#pragma unroll
        for (int f = 0; f < D; ++f) { wi[f] = w0[f]; wj[f] = w0[D + f]; }
        for (int nl = 0; nl < nmax; ++nl) {
            const float* xv = &xl[nl * 52];
            float a0 = 0.f, a1 = 0.f;
#pragma unroll
            for (int f = 0; f < D; ++f) { a0 += xv[f] * wi[f]; a1 += xv[f] * wj[f]; }
            ai[(n0 + nl) * TD + o] = a0;
            aj[(n0 + nl) * TD + o] = a1;
        }
    }
}

// Fused: CSR edge aggregation (sum/sumsq/min/max over aj rows, base from ai)
// -> agg in LDS -> post-NN matvec (identity/amp/atten folded to 3 dots)
// -> 50x50 linear -> hraw. 8 nodes per block (one node per wave, 2 rounds).
#define NB 8
__global__ __launch_bounds__(256) void k_aggpost(
    const float* __restrict__ h, const float* __restrict__ ai,
    const float* __restrict__ aj, const int* __restrict__ offs,
    const int* __restrict__ csr_src, const float* __restrict__ preB,  // [TD]
    const float* __restrict__ postW,  // [T][FOUT][650]
    const float* __restrict__ postB,  // [50]
    const float* __restrict__ linW,   // [50][50]
    const float* __restrict__ linB,   // [50]
    const float* __restrict__ avg_accum, float* __restrict__ hraw) {
    __shared__ float agg[NB * 1000];   // [nl][t*200 + {mean|mn|mx|std}*50 + g]
    __shared__ float xr[NB * 52];
    __shared__ float yr[NB * 52];
    __shared__ float scs[NB], iscs[NB];
    int n0 = blockIdx.x * NB;

    for (int k = threadIdx.x; k < NB * D; k += 256) {
        int nl = k / D, f = k % D;
        xr[nl * 52 + f] = h[(n0 + nl) * D + f];
    }
    if (threadIdx.x < NB) {
        int n = n0 + threadIdx.x;
        int dg = offs[n + 1] - offs[n];
        float cnt = (float)max(dg, 1);
        float avg = avg_accum[0] * (1.0f / NN);
        float sc = logf(cnt + 1.0f) / avg;
        scs[threadIdx.x] = sc;
        iscs[threadIdx.x] = 1.0f / sc;
    }

    int wave = threadIdx.x >> 6, lane = threadIdx.x & 63;
    for (int nl = wave; nl < NB; nl += 4) {
        int n = n0 + nl;
        int e0 = offs[n], e1 = offs[n + 1];
        float s1[4] = {0.f, 0.f, 0.f, 0.f}, s2[4] = {0.f, 0.f, 0.f, 0.f};
        float mn[4] = {INFINITY, INFINITY, INFINITY, INFINITY};
        float mx[4] = {-INFINITY, -INFINITY, -INFINITY, -INFINITY};
        int s_next = (e0 < e1) ? csr_src[e0] : 0;
        for (int e = e0; e < e1; ++e) {
            int s = s_next;
            if (e + 1 < e1) s_next = csr_src[e + 1];
            const float* ajr = aj + s * TD;
#pragma unroll
            for (int k = 0; k < 4; ++k) {
                int f = lane + 64 * k;
                if (f < TD) {
                    float v = ajr[f];
                    s1[k] += v; s2[k] += v * v;
                    mn[k] = fminf(mn[k], v); mx[k] = fmaxf(mx[k], v);
                }
            }
        }
        int dg = e1 - e0;
#pragma unroll
        for (int k = 0; k < 4; ++k) {
            int f = lane + 64 * k;
            if (f < TD) {
                float base = ai[n * TD + f] + preB[f];
                float mean, stdv, mnv, mxv;
                if (dg > 0) {
                    float inv = 1.0f / (float)dg;
                    float m1 = s1[k] * inv;
                    mean = base + m1;
                    float var = fmaxf(s2[k] * inv - m1 * m1, 0.f);
                    stdv = sqrtf(var + EPS);
                    mnv = base + mn[k]; mxv = base + mx[k];
                } else {  // torch_scatter empty: sum->0 (cnt=1), min/max->0, std=sqrt(eps)
                    mean = 0.f; stdv = sqrtf(EPS); mnv = 0.f; mxv = 0.f;
                }
                int t = f / D, g = f % D;
                float* a = &agg[nl * 1000 + t * 200 + g];
                a[0] = mean; a[50] = mnv; a[100] = mxv; a[150] = stdv;
            }
        }
    }
    __syncthreads();

    // post-NN: y[nl][o] for o=t*10+go; 650-long dot split as x(50)+3x200
    for (int k = threadIdx.x; k < NB * 50; k += 256) {
        int o = k >> 3, nl = k & 7;
        int t = o / FOUT;
        const float* w = postW + o * 650;
        const float* ar = &agg[nl * 1000 + t * 200];
        const float* xv = &xr[nl * 52];
        float accx = 0.f;
        const float2* wx = (const float2*)w;
        const float2* xv2 = (const float2*)xv;
#pragma unroll
        for (int j = 0; j < 25; ++j) {
            float2 a2 = xv2[j], b2 = wx[j];
            accx += a2.x * b2.x + a2.y * b2.y;
        }
        float d1 = 0.f, d2 = 0.f, d3 = 0.f;
        const float2* w1 = (const float2*)(w + 50);
        const float2* w2 = (const float2*)(w + 250);
        const float2* w3 = (const float2*)(w + 450);
        const float2* av = (const float2*)ar;
#pragma unroll 4
        for (int j = 0; j < 100; ++j) {
            float2 a2 = av[j];
            float2 b1 = w1[j], b2 = w2[j], b3 = w3[j];
            d1 += b1.x * a2.x + b1.y * a2.y;
            d2 += b2.x * a2.x + b2.y * a2.y;
            d3 += b3.x * a2.x + b3.y * a2.y;
        }
        yr[nl * 52 + o] = postB[o] + accx + d1 + scs[nl] * d2 + iscs[nl] * d3;
    }
    __syncthreads();

    // lin: hraw = y @ linW^T + linB
    for (int k = threadIdx.x; k < NB * 50; k += 256) {
        int nl = k / 50, c = k % 50;
        const float* w = linW + c * 50;
        const float* yv = &yr[nl * 52];
        float acc = linB[c];
#pragma unroll
        for (int q = 0; q < 50; ++q) acc += w[q] * yv[q];
        hraw[(n0 + nl) * 50 + c] = acc;
    }
}

__global__ void k_bnstats(const float* __restrict__ hraw, float* __restrict__ bn) {
    __shared__ float ls[50], lq[50];
    for (int k = threadIdx.x; k < 50; k += 256) { ls[k] = 0.f; lq[k] = 0.f; }
    __syncthreads();
    for (int idx = blockIdx.x * 256 + threadIdx.x; idx < NN * D; idx += gridDim.x * 256) {
        float v = hraw[idx];
        int c = idx % D;
        atomicAdd(&ls[c], v);
        atomicAdd(&lq[c], v * v);
    }
    __syncthreads();
    for (int k = threadIdx.x; k < 50; k += 256) {
        atomicAdd(&bn[k], ls[k]);
        atomicAdd(&bn[50 + k], lq[k]);
    }
}

__global__ void k_bnapply(const float* __restrict__ hraw, const float* __restrict__ bn,
                          const float* __restrict__ gamma, const float* __restrict__ beta,
                          float* __restrict__ h) {
    int idx = blockIdx.x * 256 + threadIdx.x;
    if (idx < NN * D) {
        int c = idx % D;
        float mean = bn[c] * (1.0f / NN);
        float var = bn[50 + c] * (1.0f / NN) - mean * mean;
        float v = gamma[c] * (hraw[idx] - mean) * rsqrtf(var + EPS) + beta[c];
        h[idx] = fmaxf(v, 0.f);
    }
}

__global__ void k_mlp(const float* __restrict__ h, const float* __restrict__ W1,
                      const float* __restrict__ b1, const float* __restrict__ W2,
                      const float* __restrict__ b2, float* __restrict__ out) {
    int n = blockIdx.x * 256 + threadIdx.x;
    if (n >= NN) return;
    float hv[50];
#pragma unroll
    for (int f = 0; f < 50; ++f) hv[f] = h[n * 50 + f];
    float s = b2[0];
    for (int o = 0; o < 25; ++o) {
        float a = b1[o];
        const float* w = W1 + o * 50;
#pragma unroll
        for (int f = 0; f < 50; ++f) a += w[f] * hv[f];
        s += W2[o] * fmaxf(a, 0.f);
    }
    out[n] = 1.0f / (1.0f + expf(-s));
}

// ------------------------------------------------------------------ launch
extern "C" void kernel_launch(void* const* d_in, const int* in_sizes, int n_in,
                              void* d_out, int out_size, void* d_ws, size_t ws_size,
                              hipStream_t stream) {
    const int* x = (const int*)d_in[0];
    const int* ei = (const int*)d_in[1];
    const int* src = ei;
    const int* dst = ei + NE;
    const float* emb   = (const float*)d_in[4];
    const float* preW  = (const float*)d_in[5];
    const float* preB  = (const float*)d_in[6];
    const float* postW = (const float*)d_in[7];
    const float* postB = (const float*)d_in[8];
    const float* linW  = (const float*)d_in[9];
    const float* linB  = (const float*)d_in[10];
    const float* gamma = (const float*)d_in[11];
    const float* beta  = (const float*)d_in[12];
    const float* W1 = (const float*)d_in[13];
    const float* b1 = (const float*)d_in[14];
    const float* W2 = (const float*)d_in[15];
    const float* b2 = (const float*)d_in[16];
    float* outp = (float*)d_out;

    char* wsp = (char*)d_ws;
    size_t off = 0;
    auto alloc = [&](size_t bytes) {
        void* p = wsp + off;
        off = (off + bytes + 255) & ~(size_t)255;
        return p;
    };
    int* deg    = (int*)alloc(NN * 4);
    int* cursor = (int*)alloc(NN * 4);
    int* offs   = (int*)alloc((NN + 1) * 4);
    int* csr    = (int*)alloc(NE * 4);
    float* bn   = (float*)alloc(512);          // [0:50) sum, [50:100) sq, [100] avg_log
    float* h    = (float*)alloc((size_t)NN * D * 4);
    float* hraw = (float*)alloc((size_t)NN * D * 4);
    float* ai   = (float*)alloc((size_t)NN * TD * 4);
    float* aj   = (float*)alloc((size_t)NN * TD * 4);
    (void)ws_size; (void)in_sizes; (void)n_in; (void)out_size;

    hipMemsetAsync(deg, 0, NN * 4, stream);
    hipMemsetAsync(cursor, 0, NN * 4, stream);
    hipMemsetAsync(bn, 0, 512, stream);

    k_deg<<<(NE + 255) / 256, 256, 0, stream>>>(dst, deg);
    k_scan<<<1, 1024, 0, stream>>>(deg, offs);
    k_csr<<<(NE + 255) / 256, 256, 0, stream>>>(src, dst, offs, cursor, csr);
    k_avglog<<<(NN + 255) / 256, 256, 0, stream>>>(deg, bn + 100);
    k_emb<<<(NN * D + 255) / 256, 256, 0, stream>>>(x, emb, h);

    for (int l = 0; l < 4; ++l) {
        k_pre<<<(NN + PRE_NT - 1) / PRE_NT, 256, 0, stream>>>(h, preW + l * TD * 100, ai, aj);
        k_aggpost<<<NN / NB, 256, 0, stream>>>(h, ai, aj, offs, csr,
                                               preB + l * TD, postW + l * 32500,
                                               postB + l * 50, linW + l * 2500,
                                               linB + l * 50, bn + 100, hraw);
        hipMemsetAsync(bn, 0, 400, stream);   // keep bn[100] (avg_log) intact
        k_bnstats<<<200, 256, 0, stream>>>(hraw, bn);
        k_bnapply<<<(NN * D + 255) / 256, 256, 0, stream>>>(hraw, bn, gamma + l * 50,
                                                            beta + l * 50, h);
    }
    k_mlp<<<(NN + 255) / 256, 256, 0, stream>>>(h, W1, b1, W2, b2, outp);
}

// Round 2
// 1166.292 us; speedup vs baseline: 1.1084x; 1.1084x over previous
//
#include <hip/hip_runtime.h>
#include <math.h>

#define NN 20000
#define NE 320000
#define D 50
#define TOWERS 5
#define TD 250      // TOWERS*D
#define ASTR 256    // padded row stride for ai/aj (float4-friendly)
#define FOUT 10
#define EPS 1e-5f

// ------------------------------------------------------------------ setup
__global__ void k_deg(const int* __restrict__ dst, int* __restrict__ deg) {
    int e = blockIdx.x * 256 + threadIdx.x;
    if (e < NE) atomicAdd(&deg[dst[e]], 1);
}

__global__ void k_scan(const int* __restrict__ deg, int* __restrict__ offs) {
    __shared__ int buf[1024];
    __shared__ int carry;
    int tid = threadIdx.x;
    if (tid == 0) carry = 0;
    __syncthreads();
    for (int base = 0; base < NN; base += 1024) {
        int i = base + tid;
        int v = (i < NN) ? deg[i] : 0;
        buf[tid] = v;
        __syncthreads();
        for (int off = 1; off < 1024; off <<= 1) {
            int t = (tid >= off) ? buf[tid - off] : 0;
            __syncthreads();
            buf[tid] += t;
            __syncthreads();
        }
        int excl = carry + buf[tid] - v;   // exclusive prefix
        if (i < NN) offs[i] = excl;
        __syncthreads();
        if (tid == 0) carry += buf[1023];
        __syncthreads();
    }
    if (tid == 0) offs[NN] = carry;        // == NE
}

__global__ void k_csr(const int* __restrict__ src, const int* __restrict__ dst,
                      const int* __restrict__ offs, int* __restrict__ cursor,
                      int* __restrict__ csr_src) {
    int e = blockIdx.x * 256 + threadIdx.x;
    if (e < NE) {
        int d = dst[e];
        int slot = atomicAdd(&cursor[d], 1);
        csr_src[offs[d] + slot] = src[e];
    }
}

__global__ void k_avglog(const int* __restrict__ deg, float* __restrict__ accum) {
    int n = blockIdx.x * 256 + threadIdx.x;
    float v = (n < NN) ? logf((float)deg[n] + 1.0f) : 0.0f;
    for (int o = 32; o > 0; o >>= 1) v += __shfl_down(v, o);
    __shared__ float wsum[4];
    int lane = threadIdx.x & 63, w = threadIdx.x >> 6;
    if (lane == 0) wsum[w] = v;
    __syncthreads();
    if (threadIdx.x == 0) atomicAdd(accum, wsum[0] + wsum[1] + wsum[2] + wsum[3]);
}

__global__ void k_emb(const int* __restrict__ x, const float* __restrict__ emb,
                      float* __restrict__ h) {
    int idx = blockIdx.x * 256 + threadIdx.x;
    if (idx < NN * D) {
        int n = idx / D, c = idx % D;
        h[idx] = emb[x[n] * D + c];
    }
}

// ------------------------------------------------------------- per layer
// ai/aj: per-node pre-NN split (x_i part / x_j part), rows padded to ASTR=256
// with zero fill so the aggregation loads unguarded float4s.
#define PRE_NT 64
__global__ __launch_bounds__(256) void k_pre(const float* __restrict__ h,
                                             const float* __restrict__ preW, // [TD][2D]
                                             float* __restrict__ ai,
                                             float* __restrict__ aj) {
    __shared__ float xl[PRE_NT * 52];
    int n0 = blockIdx.x * PRE_NT;
    int nmax = min(PRE_NT, NN - n0);
    for (int k = threadIdx.x; k < nmax * D; k += 256) {
        int nl = k / D, f = k % D;
        xl[nl * 52 + f] = h[(n0 + nl) * D + f];
    }
    __syncthreads();
    int o = threadIdx.x;
    if (o < TD) {
        const float* w0 = preW + o * (2 * D);
        float wi[D], wj[D];
#pragma unroll
        for (int f = 0; f < D; ++f) { wi[f] = w0[f]; wj[f] = w0[D + f]; }
        for (int nl = 0; nl < nmax; ++nl) {
            const float* xv = &xl[nl * 52];
            float a0 = 0.f, a1 = 0.f;
#pragma unroll
            for (int f = 0; f < D; ++f) { a0 += xv[f] * wi[f]; a1 += xv[f] * wj[f]; }
            ai[(size_t)(n0 + nl) * ASTR + o] = a0;
            aj[(size_t)(n0 + nl) * ASTR + o] = a1;
        }
    } else if (o < ASTR) {                    // zero-fill pad columns
        for (int nl = 0; nl < nmax; ++nl) {
            ai[(size_t)(n0 + nl) * ASTR + o] = 0.f;
            aj[(size_t)(n0 + nl) * ASTR + o] = 0.f;
        }
    }
}

// Fused: CSR edge aggregation (sum/sumsq/min/max over padded aj rows, base
// from ai) -> agg in LDS -> post-NN matvec -> 50x50 linear -> hraw.
// 512 threads = 8 waves; one node per wave; lane owns features 4*lane..4*lane+3
// via a single float4 load per edge-row; edge loop unrolled x4 for MLP.
#define NB 8
__global__ __launch_bounds__(512) void k_aggpost(
    const float* __restrict__ h, const float* __restrict__ ai,
    const float* __restrict__ aj, const int* __restrict__ offs,
    const int* __restrict__ csr_src, const float* __restrict__ preB,  // [TD]
    const float* __restrict__ postW,  // [T][FOUT][650]
    const float* __restrict__ postB,  // [50]
    const float* __restrict__ linW,   // [50][50]
    const float* __restrict__ linB,   // [50]
    const float* __restrict__ avg_accum, float* __restrict__ hraw) {
    __shared__ float agg[NB * 1000];   // [nl][t*200 + {mean|mn|mx|std}*50 + g]
    __shared__ float xr[NB * 52];
    __shared__ float yr[NB * 52];
    __shared__ float scs[NB], iscs[NB];
    int n0 = blockIdx.x * NB;
    int tid = threadIdx.x;

    for (int k = tid; k < NB * D; k += 512) {
        int nl = k / D, f = k % D;
        xr[nl * 52 + f] = h[(n0 + nl) * D + f];
    }
    if (tid < NB) {
        int n = n0 + tid;
        int dg = offs[n + 1] - offs[n];
        float cnt = (float)max(dg, 1);
        float avg = avg_accum[0] * (1.0f / NN);
        float sc = logf(cnt + 1.0f) / avg;
        scs[tid] = sc;
        iscs[tid] = 1.0f / sc;
    }

    int wave = tid >> 6, lane = tid & 63;
    {
        int nl = wave;                      // one node per wave
        int n = n0 + nl;
        int e0 = offs[n], e1 = offs[n + 1];
        float s1x = 0.f, s1y = 0.f, s1z = 0.f, s1w = 0.f;
        float s2x = 0.f, s2y = 0.f, s2z = 0.f, s2w = 0.f;
        float mnx = INFINITY, mny = INFINITY, mnz = INFINITY, mnw = INFINITY;
        float mxx = -INFINITY, mxy = -INFINITY, mxz = -INFINITY, mxw = -INFINITY;
        const float4* ajv = (const float4*)aj;   // row stride = 64 float4
        int e = e0;
        for (; e + 4 <= e1; e += 4) {
            int sa = csr_src[e], sb = csr_src[e + 1];
            int sc2 = csr_src[e + 2], sd = csr_src[e + 3];
            float4 va = ajv[(size_t)sa * 64 + lane];
            float4 vb = ajv[(size_t)sb * 64 + lane];
            float4 vc = ajv[(size_t)sc2 * 64 + lane];
            float4 vd = ajv[(size_t)sd * 64 + lane];
            s1x += (va.x + vb.x) + (vc.x + vd.x);
            s1y += (va.y + vb.y) + (vc.y + vd.y);
            s1z += (va.z + vb.z) + (vc.z + vd.z);
            s1w += (va.w + vb.w) + (vc.w + vd.w);
            s2x += va.x * va.x + vb.x * vb.x + vc.x * vc.x + vd.x * vd.x;
            s2y += va.y * va.y + vb.y * vb.y + vc.y * vc.y + vd.y * vd.y;
            s2z += va.z * va.z + vb.z * vb.z + vc.z * vc.z + vd.z * vd.z;
            s2w += va.w * va.w + vb.w * vb.w + vc.w * vc.w + vd.w * vd.w;
            mnx = fminf(mnx, fminf(fminf(va.x, vb.x), fminf(vc.x, vd.x)));
            mny = fminf(mny, fminf(fminf(va.y, vb.y), fminf(vc.y, vd.y)));
            mnz = fminf(mnz, fminf(fminf(va.z, vb.z), fminf(vc.z, vd.z)));
            mnw = fminf(mnw, fminf(fminf(va.w, vb.w), fminf(vc.w, vd.w)));
            mxx = fmaxf(mxx, fmaxf(fmaxf(va.x, vb.x), fmaxf(vc.x, vd.x)));
            mxy = fmaxf(mxy, fmaxf(fmaxf(va.y, vb.y), fmaxf(vc.y, vd.y)));
            mxz = fmaxf(mxz, fmaxf(fmaxf(va.z, vb.z), fmaxf(vc.z, vd.z)));
            mxw = fmaxf(mxw, fmaxf(fmaxf(va.w, vb.w), fmaxf(vc.w, vd.w)));
        }
        for (; e < e1; ++e) {
            float4 va = ajv[(size_t)csr_src[e] * 64 + lane];
            s1x += va.x; s1y += va.y; s1z += va.z; s1w += va.w;
            s2x += va.x * va.x; s2y += va.y * va.y;
            s2z += va.z * va.z; s2w += va.w * va.w;
            mnx = fminf(mnx, va.x); mny = fminf(mny, va.y);
            mnz = fminf(mnz, va.z); mnw = fminf(mnw, va.w);
            mxx = fmaxf(mxx, va.x); mxy = fmaxf(mxy, va.y);
            mxz = fmaxf(mxz, va.z); mxw = fmaxf(mxw, va.w);
        }
        int dg = e1 - e0;
        float4 aiv = ((const float4*)ai)[(size_t)n * 64 + lane];
        float s1a[4] = {s1x, s1y, s1z, s1w};
        float s2a[4] = {s2x, s2y, s2z, s2w};
        float mna[4] = {mnx, mny, mnz, mnw};
        float mxa[4] = {mxx, mxy, mxz, mxw};
        float aia[4] = {aiv.x, aiv.y, aiv.z, aiv.w};
#pragma unroll
        for (int k = 0; k < 4; ++k) {
            int f = 4 * lane + k;
            if (f < TD) {
                float base = aia[k] + preB[f];
                float mean, stdv, mnv, mxv;
                if (dg > 0) {
                    float inv = 1.0f / (float)dg;
                    float m1 = s1a[k] * inv;
                    mean = base + m1;
                    float var = fmaxf(s2a[k] * inv - m1 * m1, 0.f);
                    stdv = sqrtf(var + EPS);
                    mnv = base + mna[k]; mxv = base + mxa[k];
                } else {  // torch_scatter empty: sum->0 (cnt=1), min/max->0
                    mean = 0.f; stdv = sqrtf(EPS); mnv = 0.f; mxv = 0.f;
                }
                int t = f / D, g = f % D;
                float* a = &agg[nl * 1000 + t * 200 + g];
                a[0] = mean; a[50] = mnv; a[100] = mxv; a[150] = stdv;
            }
        }
    }
    __syncthreads();

    // post-NN: y[nl][o] for o=t*10+go; 650-long dot split as x(50)+3x200
    if (tid < NB * 50) {
        int o = tid >> 3, nl = tid & 7;
        int t = o / FOUT;
        const float* w = postW + o * 650;
        const float* ar = &agg[nl * 1000 + t * 200];
        const float* xv = &xr[nl * 52];
        float accx = 0.f;
        const float2* wx = (const float2*)w;
        const float2* xv2 = (const float2*)xv;
#pragma unroll
        for (int j = 0; j < 25; ++j) {
            float2 a2 = xv2[j], b2 = wx[j];
            accx += a2.x * b2.x + a2.y * b2.y;
        }
        float d1 = 0.f, d2 = 0.f, d3 = 0.f;
        const float2* w1 = (const float2*)(w + 50);
        const float2* w2 = (const float2*)(w + 250);
        const float2* w3 = (const float2*)(w + 450);
        const float2* av = (const float2*)ar;
#pragma unroll 4
        for (int j = 0; j < 100; ++j) {
            float2 a2 = av[j];
            float2 b1 = w1[j], b2 = w2[j], b3 = w3[j];
            d1 += b1.x * a2.x + b1.y * a2.y;
            d2 += b2.x * a2.x + b2.y * a2.y;
            d3 += b3.x * a2.x + b3.y * a2.y;
        }
        yr[nl * 52 + o] = postB[o] + accx + d1 + scs[nl] * d2 + iscs[nl] * d3;
    }
    __syncthreads();

    // lin: hraw = y @ linW^T + linB
    if (tid < NB * 50) {
        int nl = tid / 50, c = tid % 50;
        const float* w = linW + c * 50;
        const float* yv = &yr[nl * 52];
        float acc = linB[c];
#pragma unroll
        for (int q = 0; q < 50; ++q) acc += w[q] * yv[q];
        hraw[(n0 + nl) * 50 + c] = acc;
    }
}

__global__ void k_bnstats(const float* __restrict__ hraw, float* __restrict__ bn) {
    __shared__ float ls[50], lq[50];
    for (int k = threadIdx.x; k < 50; k += 256) { ls[k] = 0.f; lq[k] = 0.f; }
    __syncthreads();
    for (int idx = blockIdx.x * 256 + threadIdx.x; idx < NN * D; idx += gridDim.x * 256) {
        float v = hraw[idx];
        int c = idx % D;
        atomicAdd(&ls[c], v);
        atomicAdd(&lq[c], v * v);
    }
    __syncthreads();
    for (int k = threadIdx.x; k < 50; k += 256) {
        atomicAdd(&bn[k], ls[k]);
        atomicAdd(&bn[50 + k], lq[k]);
    }
}

__global__ void k_bnapply(const float* __restrict__ hraw, const float* __restrict__ bn,
                          const float* __restrict__ gamma, const float* __restrict__ beta,
                          float* __restrict__ h) {
    int idx = blockIdx.x * 256 + threadIdx.x;
    if (idx < NN * D) {
        int c = idx % D;
        float mean = bn[c] * (1.0f / NN);
        float var = bn[50 + c] * (1.0f / NN) - mean * mean;
        float v = gamma[c] * (hraw[idx] - mean) * rsqrtf(var + EPS) + beta[c];
        h[idx] = fmaxf(v, 0.f);
    }
}

__global__ void k_mlp(const float* __restrict__ h, const float* __restrict__ W1,
                      const float* __restrict__ b1, const float* __restrict__ W2,
                      const float* __restrict__ b2, float* __restrict__ out) {
    int n = blockIdx.x * 256 + threadIdx.x;
    if (n >= NN) return;
    float hv[50];
#pragma unroll
    for (int f = 0; f < 50; ++f) hv[f] = h[n * 50 + f];
    float s = b2[0];
    for (int o = 0; o < 25; ++o) {
        float a = b1[o];
        const float* w = W1 + o * 50;
#pragma unroll
        for (int f = 0; f < 50; ++f) a += w[f] * hv[f];
        s += W2[o] * fmaxf(a, 0.f);
    }
    out[n] = 1.0f / (1.0f + expf(-s));
}

// ------------------------------------------------------------------ launch
extern "C" void kernel_launch(void* const* d_in, const int* in_sizes, int n_in,
                              void* d_out, int out_size, void* d_ws, size_t ws_size,
                              hipStream_t stream) {
    const int* x = (const int*)d_in[0];
    const int* ei = (const int*)d_in[1];
    const int* src = ei;
    const int* dst = ei + NE;
    const float* emb   = (const float*)d_in[4];
    const float* preW  = (const float*)d_in[5];
    const float* preB  = (const float*)d_in[6];
    const float* postW = (const float*)d_in[7];
    const float* postB = (const float*)d_in[8];
    const float* linW  = (const float*)d_in[9];
    const float* linB  = (const float*)d_in[10];
    const float* gamma = (const float*)d_in[11];
    const float* beta  = (const float*)d_in[12];
    const float* W1 = (const float*)d_in[13];
    const float* b1 = (const float*)d_in[14];
    const float* W2 = (const float*)d_in[15];
    const float* b2 = (const float*)d_in[16];
    float* outp = (float*)d_out;

    char* wsp = (char*)d_ws;
    size_t off = 0;
    auto alloc = [&](size_t bytes) {
        void* p = wsp + off;
        off = (off + bytes + 1023) & ~(size_t)1023;
        return p;
    };
    int* deg    = (int*)alloc(NN * 4);
    int* cursor = (int*)alloc(NN * 4);
    int* offs   = (int*)alloc((NN + 1) * 4);
    int* csr    = (int*)alloc(NE * 4);
    float* bn   = (float*)alloc(512);          // [0:50) sum, [50:100) sq, [100] avg_log
    float* h    = (float*)alloc((size_t)NN * D * 4);
    float* hraw = (float*)alloc((size_t)NN * D * 4);
    float* ai   = (float*)alloc((size_t)NN * ASTR * 4);
    float* aj   = (float*)alloc((size_t)NN * ASTR * 4);
    (void)ws_size; (void)in_sizes; (void)n_in; (void)out_size;

    hipMemsetAsync(deg, 0, NN * 4, stream);
    hipMemsetAsync(cursor, 0, NN * 4, stream);
    hipMemsetAsync(bn, 0, 512, stream);

    k_deg<<<(NE + 255) / 256, 256, 0, stream>>>(dst, deg);
    k_scan<<<1, 1024, 0, stream>>>(deg, offs);
    k_csr<<<(NE + 255) / 256, 256, 0, stream>>>(src, dst, offs, cursor, csr);
    k_avglog<<<(NN + 255) / 256, 256, 0, stream>>>(deg, bn + 100);
    k_emb<<<(NN * D + 255) / 256, 256, 0, stream>>>(x, emb, h);

    for (int l = 0; l < 4; ++l) {
        k_pre<<<(NN + PRE_NT - 1) / PRE_NT, 256, 0, stream>>>(h, preW + l * TD * 100, ai, aj);
        k_aggpost<<<NN / NB, 512, 0, stream>>>(h, ai, aj, offs, csr,
                                               preB + l * TD, postW + l * 32500,
                                               postB + l * 50, linW + l * 2500,
                                               linB + l * 50, bn + 100, hraw);
        hipMemsetAsync(bn, 0, 400, stream);   // keep bn[100] (avg_log) intact
        k_bnstats<<<200, 256, 0, stream>>>(hraw, bn);
        k_bnapply<<<(NN * D + 255) / 256, 256, 0, stream>>>(hraw, bn, gamma + l * 50,
                                                            beta + l * 50, h);
    }
    k_mlp<<<(NN + 255) / 256, 256, 0, stream>>>(h, W1, b1, W2, b2, outp);
}

// Round 3
// 1159.529 us; speedup vs baseline: 1.1148x; 1.0058x over previous
//
#include <hip/hip_runtime.h>
#include <math.h>

#define NN 20000
#define NE 320000
#define D 50
#define TOWERS 5
#define TD 250      // TOWERS*D
#define ASTR 256    // padded row stride for ai/aj (float4-friendly)
#define FOUT 10
#define EPS 1e-5f

// ------------------------------------------------------------------ setup
__global__ void k_deg(const int* __restrict__ dst, int* __restrict__ deg) {
    int e = blockIdx.x * 256 + threadIdx.x;
    if (e < NE) atomicAdd(&deg[dst[e]], 1);
}

__global__ void k_scan(const int* __restrict__ deg, int* __restrict__ offs) {
    __shared__ int buf[1024];
    __shared__ int carry;
    int tid = threadIdx.x;
    if (tid == 0) carry = 0;
    __syncthreads();
    for (int base = 0; base < NN; base += 1024) {
        int i = base + tid;
        int v = (i < NN) ? deg[i] : 0;
        buf[tid] = v;
        __syncthreads();
        for (int off = 1; off < 1024; off <<= 1) {
            int t = (tid >= off) ? buf[tid - off] : 0;
            __syncthreads();
            buf[tid] += t;
            __syncthreads();
        }
        int excl = carry + buf[tid] - v;   // exclusive prefix
        if (i < NN) offs[i] = excl;
        __syncthreads();
        if (tid == 0) carry += buf[1023];
        __syncthreads();
    }
    if (tid == 0) offs[NN] = carry;        // == NE
}

__global__ void k_csr(const int* __restrict__ src, const int* __restrict__ dst,
                      const int* __restrict__ offs, int* __restrict__ cursor,
                      int* __restrict__ csr_src) {
    int e = blockIdx.x * 256 + threadIdx.x;
    if (e < NE) {
        int d = dst[e];
        int slot = atomicAdd(&cursor[d], 1);
        csr_src[offs[d] + slot] = src[e];
    }
}

__global__ void k_avglog(const int* __restrict__ deg, float* __restrict__ accum) {
    int n = blockIdx.x * 256 + threadIdx.x;
    float v = (n < NN) ? logf((float)deg[n] + 1.0f) : 0.0f;
    for (int o = 32; o > 0; o >>= 1) v += __shfl_down(v, o);
    __shared__ float wsum[4];
    int lane = threadIdx.x & 63, w = threadIdx.x >> 6;
    if (lane == 0) wsum[w] = v;
    __syncthreads();
    if (threadIdx.x == 0) atomicAdd(accum, wsum[0] + wsum[1] + wsum[2] + wsum[3]);
}

__global__ void k_emb(const int* __restrict__ x, const float* __restrict__ emb,
                      float* __restrict__ h) {
    int idx = blockIdx.x * 256 + threadIdx.x;
    if (idx < NN * D) {
        int n = idx / D, c = idx % D;
        h[idx] = emb[x[n] * D + c];
    }
}

// ------------------------------------------------------------- per layer
// ai/aj: per-node pre-NN split (x_i part / x_j part), rows padded to ASTR=256
// with zero fill so the aggregation loads unguarded float4s.
#define PRE_NT 64
__global__ __launch_bounds__(256) void k_pre(const float* __restrict__ h,
                                             const float* __restrict__ preW, // [TD][2D]
                                             float* __restrict__ ai,
                                             float* __restrict__ aj) {
    __shared__ float xl[PRE_NT * 52];
    int n0 = blockIdx.x * PRE_NT;
    int nmax = min(PRE_NT, NN - n0);
    for (int k = threadIdx.x; k < nmax * D; k += 256) {
        int nl = k / D, f = k % D;
        xl[nl * 52 + f] = h[(n0 + nl) * D + f];
    }
    __syncthreads();
    int o = threadIdx.x;
    if (o < TD) {
        const float* w0 = preW + o * (2 * D);
        float wi[D], wj[D];
#pragma unroll
        for (int f = 0; f < D; ++f) { wi[f] = w0[f]; wj[f] = w0[D + f]; }
        for (int nl = 0; nl < nmax; ++nl) {
            const float* xv = &xl[nl * 52];
            float a0 = 0.f, a1 = 0.f;
#pragma unroll
            for (int f = 0; f < D; ++f) { a0 += xv[f] * wi[f]; a1 += xv[f] * wj[f]; }
            ai[(size_t)(n0 + nl) * ASTR + o] = a0;
            aj[(size_t)(n0 + nl) * ASTR + o] = a1;
        }
    } else if (o < ASTR) {                    // zero-fill pad columns
        for (int nl = 0; nl < nmax; ++nl) {
            ai[(size_t)(n0 + nl) * ASTR + o] = 0.f;
            aj[(size_t)(n0 + nl) * ASTR + o] = 0.f;
        }
    }
}

// Fused: CSR edge aggregation -> agg in LDS -> post-NN matvec -> 50x50 linear.
// 512 threads = 8 waves; one node per wave; lane owns features 4*lane..4*lane+3.
// Edge indices prefetched into per-lane registers (one coalesced load per 64),
// broadcast via __shfl, then 8 independent float4 row-loads in flight.
#define NB 8

#define ACC8(v) do { \
    s1x += v.x; s1y += v.y; s1z += v.z; s1w += v.w; \
    s2x += v.x * v.x; s2y += v.y * v.y; s2z += v.z * v.z; s2w += v.w * v.w; \
    mnx = fminf(mnx, v.x); mny = fminf(mny, v.y); \
    mnz = fminf(mnz, v.z); mnw = fminf(mnw, v.w); \
    mxx = fmaxf(mxx, v.x); mxy = fmaxf(mxy, v.y); \
    mxz = fmaxf(mxz, v.z); mxw = fmaxf(mxw, v.w); \
} while (0)

__global__ __launch_bounds__(512) void k_aggpost(
    const float* __restrict__ h, const float* __restrict__ ai,
    const float* __restrict__ aj, const int* __restrict__ offs,
    const int* __restrict__ csr_src, const float* __restrict__ preB,  // [TD]
    const float* __restrict__ postW,  // [T][FOUT][650]
    const float* __restrict__ postB,  // [50]
    const float* __restrict__ linW,   // [50][50]
    const float* __restrict__ linB,   // [50]
    const float* __restrict__ avg_accum, float* __restrict__ hraw) {
    __shared__ float agg[NB * 1000];   // [nl][t*200 + {mean|mn|mx|std}*50 + g]
    __shared__ float xr[NB * 52];
    __shared__ float yr[NB * 52];
    __shared__ float scs[NB], iscs[NB];
    int n0 = blockIdx.x * NB;
    int tid = threadIdx.x;

    for (int k = tid; k < NB * D; k += 512) {
        int nl = k / D, f = k % D;
        xr[nl * 52 + f] = h[(n0 + nl) * D + f];
    }
    if (tid < NB) {
        int n = n0 + tid;
        int dg = offs[n + 1] - offs[n];
        float cnt = (float)max(dg, 1);
        float avg = avg_accum[0] * (1.0f / NN);
        float sc = logf(cnt + 1.0f) / avg;
        scs[tid] = sc;
        iscs[tid] = 1.0f / sc;
    }

    int wave = tid >> 6, lane = tid & 63;
    {
        int nl = wave;                      // one node per wave
        int n = n0 + nl;
        int e0 = offs[n], e1 = offs[n + 1];
        float s1x = 0.f, s1y = 0.f, s1z = 0.f, s1w = 0.f;
        float s2x = 0.f, s2y = 0.f, s2z = 0.f, s2w = 0.f;
        float mnx = INFINITY, mny = INFINITY, mnz = INFINITY, mnw = INFINITY;
        float mxx = -INFINITY, mxy = -INFINITY, mxz = -INFINITY, mxw = -INFINITY;
        const float4* ajv = (const float4*)aj;   // row stride = 64 float4
        for (int base = e0; base < e1; base += 64) {
            int m = min(64, e1 - base);
            // one coalesced load: lane j holds csr_src[base+j]
            int sidx = csr_src[base + (lane < m ? lane : m - 1)];
            int j = 0;
            for (; j + 8 <= m; j += 8) {
                int i0 = __shfl(sidx, j + 0), i1 = __shfl(sidx, j + 1);
                int i2 = __shfl(sidx, j + 2), i3 = __shfl(sidx, j + 3);
                int i4 = __shfl(sidx, j + 4), i5 = __shfl(sidx, j + 5);
                int i6 = __shfl(sidx, j + 6), i7 = __shfl(sidx, j + 7);
                float4 v0 = ajv[(size_t)i0 * 64 + lane];
                float4 v1 = ajv[(size_t)i1 * 64 + lane];
                float4 v2 = ajv[(size_t)i2 * 64 + lane];
                float4 v3 = ajv[(size_t)i3 * 64 + lane];
                float4 v4 = ajv[(size_t)i4 * 64 + lane];
                float4 v5 = ajv[(size_t)i5 * 64 + lane];
                float4 v6 = ajv[(size_t)i6 * 64 + lane];
                float4 v7 = ajv[(size_t)i7 * 64 + lane];
                ACC8(v0); ACC8(v1); ACC8(v2); ACC8(v3);
                ACC8(v4); ACC8(v5); ACC8(v6); ACC8(v7);
            }
            for (; j < m; ++j) {
                int s = __shfl(sidx, j);
                float4 v = ajv[(size_t)s * 64 + lane];
                ACC8(v);
            }
        }
        int dg = e1 - e0;
        float4 aiv = ((const float4*)ai)[(size_t)n * 64 + lane];
        float s1a[4] = {s1x, s1y, s1z, s1w};
        float s2a[4] = {s2x, s2y, s2z, s2w};
        float mna[4] = {mnx, mny, mnz, mnw};
        float mxa[4] = {mxx, mxy, mxz, mxw};
        float aia[4] = {aiv.x, aiv.y, aiv.z, aiv.w};
#pragma unroll
        for (int k = 0; k < 4; ++k) {
            int f = 4 * lane + k;
            if (f < TD) {
                float base = aia[k] + preB[f];
                float mean, stdv, mnv, mxv;
                if (dg > 0) {
                    float inv = 1.0f / (float)dg;
                    float m1 = s1a[k] * inv;
                    mean = base + m1;
                    float var = fmaxf(s2a[k] * inv - m1 * m1, 0.f);
                    stdv = sqrtf(var + EPS);
                    mnv = base + mna[k]; mxv = base + mxa[k];
                } else {  // torch_scatter empty: sum->0 (cnt=1), min/max->0
                    mean = 0.f; stdv = sqrtf(EPS); mnv = 0.f; mxv = 0.f;
                }
                int t = f / D, g = f % D;
                float* a = &agg[nl * 1000 + t * 200 + g];
                a[0] = mean; a[50] = mnv; a[100] = mxv; a[150] = stdv;
            }
        }
    }
    __syncthreads();

    // post-NN: y[nl][o] for o=t*10+go; 650-long dot split as x(50)+3x200
    if (tid < NB * 50) {
        int o = tid >> 3, nl = tid & 7;
        int t = o / FOUT;
        const float* w = postW + o * 650;
        const float* ar = &agg[nl * 1000 + t * 200];
        const float* xv = &xr[nl * 52];
        float accx = 0.f;
        const float2* wx = (const float2*)w;
        const float2* xv2 = (const float2*)xv;
#pragma unroll
        for (int j = 0; j < 25; ++j) {
            float2 a2 = xv2[j], b2 = wx[j];
            accx += a2.x * b2.x + a2.y * b2.y;
        }
        float d1 = 0.f, d2 = 0.f, d3 = 0.f;
        const float2* w1 = (const float2*)(w + 50);
        const float2* w2 = (const float2*)(w + 250);
        const float2* w3 = (const float2*)(w + 450);
        const float2* av = (const float2*)ar;
#pragma unroll 4
        for (int j = 0; j < 100; ++j) {
            float2 a2 = av[j];
            float2 b1 = w1[j], b2 = w2[j], b3 = w3[j];
            d1 += b1.x * a2.x + b1.y * a2.y;
            d2 += b2.x * a2.x + b2.y * a2.y;
            d3 += b3.x * a2.x + b3.y * a2.y;
        }
        yr[nl * 52 + o] = postB[o] + accx + d1 + scs[nl] * d2 + iscs[nl] * d3;
    }
    __syncthreads();

    // lin: hraw = y @ linW^T + linB
    if (tid < NB * 50) {
        int nl = tid / 50, c = tid % 50;
        const float* w = linW + c * 50;
        const float* yv = &yr[nl * 52];
        float acc = linB[c];
#pragma unroll
        for (int q = 0; q < 50; ++q) acc += w[q] * yv[q];
        hraw[(n0 + nl) * 50 + c] = acc;
    }
}

__global__ void k_bnstats(const float* __restrict__ hraw, float* __restrict__ bn) {
    __shared__ float ls[50], lq[50];
    for (int k = threadIdx.x; k < 50; k += 256) { ls[k] = 0.f; lq[k] = 0.f; }
    __syncthreads();
    for (int idx = blockIdx.x * 256 + threadIdx.x; idx < NN * D; idx += gridDim.x * 256) {
        float v = hraw[idx];
        int c = idx % D;
        atomicAdd(&ls[c], v);
        atomicAdd(&lq[c], v * v);
    }
    __syncthreads();
    for (int k = threadIdx.x; k < 50; k += 256) {
        atomicAdd(&bn[k], ls[k]);
        atomicAdd(&bn[50 + k], lq[k]);
    }
}

__global__ void k_bnapply(const float* __restrict__ hraw, const float* __restrict__ bn,
                          const float* __restrict__ gamma, const float* __restrict__ beta,
                          float* __restrict__ h) {
    int idx = blockIdx.x * 256 + threadIdx.x;
    if (idx < NN * D) {
        int c = idx % D;
        float mean = bn[c] * (1.0f / NN);
        float var = bn[50 + c] * (1.0f / NN) - mean * mean;
        float v = gamma[c] * (hraw[idx] - mean) * rsqrtf(var + EPS) + beta[c];
        h[idx] = fmaxf(v, 0.f);
    }
}

__global__ void k_mlp(const float* __restrict__ h, const float* __restrict__ W1,
                      const float* __restrict__ b1, const float* __restrict__ W2,
                      const float* __restrict__ b2, float* __restrict__ out) {
    int n = blockIdx.x * 256 + threadIdx.x;
    if (n >= NN) return;
    float hv[50];
#pragma unroll
    for (int f = 0; f < 50; ++f) hv[f] = h[n * 50 + f];
    float s = b2[0];
    for (int o = 0; o < 25; ++o) {
        float a = b1[o];
        const float* w = W1 + o * 50;
#pragma unroll
        for (int f = 0; f < 50; ++f) a += w[f] * hv[f];
        s += W2[o] * fmaxf(a, 0.f);
    }
    out[n] = 1.0f / (1.0f + expf(-s));
}

// ------------------------------------------------------------------ launch
extern "C" void kernel_launch(void* const* d_in, const int* in_sizes, int n_in,
                              void* d_out, int out_size, void* d_ws, size_t ws_size,
                              hipStream_t stream) {
    const int* x = (const int*)d_in[0];
    const int* ei = (const int*)d_in[1];
    const int* src = ei;
    const int* dst = ei + NE;
    const float* emb   = (const float*)d_in[4];
    const float* preW  = (const float*)d_in[5];
    const float* preB  = (const float*)d_in[6];
    const float* postW = (const float*)d_in[7];
    const float* postB = (const float*)d_in[8];
    const float* linW  = (const float*)d_in[9];
    const float* linB  = (const float*)d_in[10];
    const float* gamma = (const float*)d_in[11];
    const float* beta  = (const float*)d_in[12];
    const float* W1 = (const float*)d_in[13];
    const float* b1 = (const float*)d_in[14];
    const float* W2 = (const float*)d_in[15];
    const float* b2 = (const float*)d_in[16];
    float* outp = (float*)d_out;

    char* wsp = (char*)d_ws;
    size_t off = 0;
    auto alloc = [&](size_t bytes) {
        void* p = wsp + off;
        off = (off + bytes + 1023) & ~(size_t)1023;
        return p;
    };
    int* deg    = (int*)alloc(NN * 4);
    int* cursor = (int*)alloc(NN * 4);
    int* offs   = (int*)alloc((NN + 1) * 4);
    int* csr    = (int*)alloc(NE * 4);
    float* bn   = (float*)alloc(512);          // [0:50) sum, [50:100) sq, [100] avg_log
    float* h    = (float*)alloc((size_t)NN * D * 4);
    float* hraw = (float*)alloc((size_t)NN * D * 4);
    float* ai   = (float*)alloc((size_t)NN * ASTR * 4);
    float* aj   = (float*)alloc((size_t)NN * ASTR * 4);
    (void)ws_size; (void)in_sizes; (void)n_in; (void)out_size;

    hipMemsetAsync(deg, 0, NN * 4, stream);
    hipMemsetAsync(cursor, 0, NN * 4, stream);
    hipMemsetAsync(bn, 0, 512, stream);

    k_deg<<<(NE + 255) / 256, 256, 0, stream>>>(dst, deg);
    k_scan<<<1, 1024, 0, stream>>>(deg, offs);
    k_csr<<<(NE + 255) / 256, 256, 0, stream>>>(src, dst, offs, cursor, csr);
    k_avglog<<<(NN + 255) / 256, 256, 0, stream>>>(deg, bn + 100);
    k_emb<<<(NN * D + 255) / 256, 256, 0, stream>>>(x, emb, h);

    for (int l = 0; l < 4; ++l) {
        k_pre<<<(NN + PRE_NT - 1) / PRE_NT, 256, 0, stream>>>(h, preW + l * TD * 100, ai, aj);
        k_aggpost<<<NN / NB, 512, 0, stream>>>(h, ai, aj, offs, csr,
                                               preB + l * TD, postW + l * 32500,
                                               postB + l * 50, linW + l * 2500,
                                               linB + l * 50, bn + 100, hraw);
        hipMemsetAsync(bn, 0, 400, stream);   // keep bn[100] (avg_log) intact
        k_bnstats<<<200, 256, 0, stream>>>(hraw, bn);
        k_bnapply<<<(NN * D + 255) / 256, 256, 0, stream>>>(hraw, bn, gamma + l * 50,
                                                            beta + l * 50, h);
    }
    k_mlp<<<(NN + 255) / 256, 256, 0, stream>>>(h, W1, b1, W2, b2, outp);
}